// Round 12
// baseline (908.043 us; speedup 1.0000x reference)
//
#include <hip/hip_runtime.h>

#define EPSV 1e-5f

typedef unsigned short u16;
typedef __attribute__((ext_vector_type(8))) _Float16 half8;
typedef __attribute__((ext_vector_type(4))) float floatx4;

__device__ __forceinline__ float h2f(u16 h) {
    return (float)__builtin_bit_cast(_Float16, h);
}
__device__ __forceinline__ u16 f2h(float f) {
    _Float16 h = (_Float16)f;
    return __builtin_bit_cast(u16, h);
}

#define GLOAD_LDS(gsrc, ldst)                                                  \
    __builtin_amdgcn_global_load_lds(                                          \
        (const __attribute__((address_space(1))) unsigned int*)(const void*)(gsrc), \
        (__attribute__((address_space(3))) unsigned int*)(void*)(ldst), 16, 0, 0)

// ---------------------------------------------------------------------------
// 256x256 phase-split NT fp16 MFMA GEMM (guide T3+T4+T5 combo).
// D[i][j] = sum_k A[i][k]*B[j][k].  BK=32, 512 threads = 8 waves (2M x 4N),
// per-wave output 128x64 = 8x4 16x16 frags, 32 MFMA per K-step per wave.
// LDS: 4 buffers x (A 256x32 + B 256x32) fp16 = 128 KB -> 1 block/CU.
//
// Schedule per K-step t (2 sub-phases):
//  ph0: issue stage A(t+2) [2 gload_lds/wave] -> s_waitcnt vmcnt(6)
//       (newer-in-flight = tile t+1's 4 + A(t+2)'s 2; guarantees tile t
//       landed; NEVER drains to 0 in steady state) -> s_barrier ->
//       ds_read A m0..7 + B n0..1 -> lgkmcnt(0) -> setprio(1) 16 MFMA.
//  ph1: issue stage B(t+2) -> ds_read B n2..3 -> lgkmcnt(0) ->
//       setprio(1) 16 MFMA -> s_barrier.
// Race proof: write at step t targets buffer (t+2)&3 == (t-2)&3; every wave
// passed end-barrier(t-1), which postdates all lgkmcnt-ordered reads of
// step t-2. vmcnt tail: t=nt-2 -> vmcnt(4); t=nt-1 -> vmcnt(0).
//
// MODE: 0 plain, 1 BN+ReLU per col j, 2 BN+ReLU per row i, 3 add fp16 addf.
// Requires I%256==0, J%256==0, K%32==0 (and K>=64).
// ---------------------------------------------------------------------------
template <int MODE, typename OUTT>
__global__ __launch_bounds__(512, 1)
void gemm256(const u16* __restrict__ A, const u16* __restrict__ B,
             OUTT* __restrict__ C_,
             const float* __restrict__ inv_, const float* __restrict__ beta_,
             const u16* __restrict__ addf,
             int K, int ldA, int ldB, int ldC,
             long strideA, long strideB, long strideC)
{
    __shared__ u16 As[4][256 * 32];
    __shared__ u16 Bs[4][256 * 32];

    const int tid = threadIdx.x;
    const int w = tid >> 6;        // wave 0..7
    const int l = tid & 63;

    // XCD-chunked bijective swizzle (all grids have nwg % 8 == 0)
    int bx = blockIdx.x, by = blockIdx.y, bz = blockIdx.z;
    {
        const int gx = gridDim.x, gy = gridDim.y;
        const int nwg = gx * gy * (int)gridDim.z;
        if ((nwg & 7) == 0) {
            const int lin = bx + gx * (by + gy * bz);
            const int swz = (lin & 7) * (nwg >> 3) + (lin >> 3);
            bx = swz % gx;
            const int t2 = swz / gx;
            by = t2 % gy;
            bz = t2 / gy;
        }
    }
    const int j0 = bx * 256;
    const int i0 = by * 256;

    const u16* Ab = A + (long)bz * strideA;
    const u16* Bb = B + (long)bz * strideB;

    // staging: issue s covers rows s*128 + w*16 + (l>>2); lane kel (l&3)*8.
    // LDS dest = rowbase*64 bytes + l*16 (linear, matches gload_lds HW rule).
    const int srow = w * 16 + (l >> 2);
    const int skel = (l & 3) * 8;

    // compute mapping
    const int wr = w >> 2;          // 0..1 (M half)
    const int wc = w & 3;           // 0..3 (N quarter)
    const int ibase = wr * 128;
    const int jbase = wc * 64;
    const int lm = l & 15;
    const int kq = l >> 4;          // 0..3

    floatx4 acc[8][4];
    #pragma unroll
    for (int a = 0; a < 8; ++a)
        #pragma unroll
        for (int b = 0; b < 4; ++b) acc[a][b] = (floatx4)(0.0f);

    auto stageA = [&](int buf, int k0) {
        #pragma unroll
        for (int s = 0; s < 2; ++s) {
            const u16* g = Ab + (long)(i0 + s * 128 + srow) * ldA + k0 + skel;
            char* d = (char*)&As[buf][0] + (s * 128 + w * 16) * 64;
            GLOAD_LDS(g, d);
        }
    };
    auto stageB = [&](int buf, int k0) {
        #pragma unroll
        for (int s = 0; s < 2; ++s) {
            const u16* g = Bb + (long)(j0 + s * 128 + srow) * ldB + k0 + skel;
            char* d = (char*)&Bs[buf][0] + (s * 128 + w * 16) * 64;
            GLOAD_LDS(g, d);
        }
    };

    const int nt = K >> 5;          // K-tiles of 32 (nt >= 2 for all shapes)
    stageA(0, 0);  stageB(0, 0);
    stageA(1, 32); stageB(1, 32);

    for (int t = 0; t < nt; ++t) {
        const u16* Ac = &As[t & 3][0];
        const u16* Bc = &Bs[t & 3][0];

        // ---------------- phase 0 ----------------
        if (t + 2 < nt) {
            stageA((t + 2) & 3, (t + 2) << 5);
            asm volatile("s_waitcnt vmcnt(6)" ::: "memory");
        } else if (t + 1 < nt) {
            asm volatile("s_waitcnt vmcnt(4)" ::: "memory");
        } else {
            asm volatile("s_waitcnt vmcnt(0)" ::: "memory");
        }
        __builtin_amdgcn_s_barrier();          // tile t visible to all waves
        __builtin_amdgcn_sched_barrier(0);

        half8 af[8], bf[4];
        #pragma unroll
        for (int m = 0; m < 8; ++m)
            af[m] = *(const half8*)&Ac[(ibase + m * 16 + lm) * 32 + kq * 8];
        #pragma unroll
        for (int n = 0; n < 2; ++n)
            bf[n] = *(const half8*)&Bc[(jbase + n * 16 + lm) * 32 + kq * 8];
        asm volatile("s_waitcnt lgkmcnt(0)" ::: "memory");
        __builtin_amdgcn_sched_barrier(0);
        __builtin_amdgcn_s_setprio(1);
        #pragma unroll
        for (int m = 0; m < 8; ++m)
            #pragma unroll
            for (int n = 0; n < 2; ++n)
                acc[m][n] = __builtin_amdgcn_mfma_f32_16x16x32_f16(
                    af[m], bf[n], acc[m][n], 0, 0, 0);
        __builtin_amdgcn_s_setprio(0);

        // ---------------- phase 1 ----------------
        if (t + 2 < nt) stageB((t + 2) & 3, (t + 2) << 5);
        #pragma unroll
        for (int n = 2; n < 4; ++n)
            bf[n] = *(const half8*)&Bc[(jbase + n * 16 + lm) * 32 + kq * 8];
        asm volatile("s_waitcnt lgkmcnt(0)" ::: "memory");
        __builtin_amdgcn_sched_barrier(0);
        __builtin_amdgcn_s_setprio(1);
        #pragma unroll
        for (int m = 0; m < 8; ++m)
            #pragma unroll
            for (int n = 2; n < 4; ++n)
                acc[m][n] = __builtin_amdgcn_mfma_f32_16x16x32_f16(
                    af[m], bf[n], acc[m][n], 0, 0, 0);
        __builtin_amdgcn_s_setprio(0);
        __builtin_amdgcn_s_barrier();          // close step: reads of t done
    }

    OUTT* Cb = C_ + (long)bz * strideC;
    const u16* addb = (MODE == 3) ? addf + (long)bz * strideC : nullptr;
    #pragma unroll
    for (int ti = 0; ti < 8; ++ti) {
        #pragma unroll
        for (int tj = 0; tj < 4; ++tj) {
            const int jj = j0 + jbase + tj * 16 + lm;
            float cinv = 0.f, cbeta = 0.f;
            if (MODE == 1) { cinv = inv_[jj]; cbeta = beta_[jj]; }
            #pragma unroll
            for (int r = 0; r < 4; ++r) {
                const int ii = i0 + ibase + ti * 16 + kq * 4 + r;
                float val = acc[ti][tj][r];
                if (MODE == 1) val = fmaxf(val * cinv + cbeta, 0.0f);
                if (MODE == 2) {
                    float iv = inv_[ii], bt = beta_[ii];
                    val = fmaxf(val * iv + bt, 0.0f);
                }
                if (MODE == 3) val += h2f(addb[(long)ii * ldC + jj]);
                if (sizeof(OUTT) == 4) {
                    ((float*)Cb)[(long)ii * ldC + jj] = val;
                } else {
                    ((u16*)Cb)[(long)ii * ldC + jj] = f2h(val);
                }
            }
        }
    }
}

// ---------------------------------------------------------------------------
// weight fp32 -> fp16 + precompute BN inv/beta
// ---------------------------------------------------------------------------
__global__ __launch_bounds__(256)
void conv_weight(const float* __restrict__ W, const float* __restrict__ g,
                 const float* __restrict__ b, const float* __restrict__ m,
                 const float* __restrict__ v,
                 u16* __restrict__ Wb, float* __restrict__ inv_,
                 float* __restrict__ beta_, int cout, long n)
{
    for (long idx = (long)blockIdx.x * 256 + threadIdx.x; idx < n;
         idx += (long)gridDim.x * 256)
        Wb[idx] = f2h(W[idx]);
    int c = blockIdx.x * 256 + threadIdx.x;
    if (c < cout) {
        float iv = g[c] * rsqrtf(v[c] + EPSV);
        inv_[c] = iv;
        beta_[c] = b[c] - m[c] * iv;
    }
}

// ---------------------------------------------------------------------------
// feature [C][N] fp32 -> featT [N][C] fp16 (32x32 tiled transpose), per batch z
// ---------------------------------------------------------------------------
__global__ __launch_bounds__(256)
void transpose_conv(const float* __restrict__ in, u16* __restrict__ out,
                    int C, int N)
{
    __shared__ float t[32][33];
    const int n0 = blockIdx.x * 32, c0 = blockIdx.y * 32;
    const float* inb = in + (long)blockIdx.z * C * N;
    u16* outb = out + (long)blockIdx.z * C * N;
    const int tx = threadIdx.x & 31, ty = threadIdx.x >> 5;  // 32 x 8
    #pragma unroll
    for (int rr = 0; rr < 32; rr += 8)
        t[ty + rr][tx] = inb[(long)(c0 + ty + rr) * N + n0 + tx];
    __syncthreads();
    #pragma unroll
    for (int rr = 0; rr < 32; rr += 8)
        outb[(long)(n0 + ty + rr) * C + c0 + tx] = f2h(t[tx][ty + rr]);
}

// ---------------------------------------------------------------------------
// Row softmax for ONE batch: reads S fp32 [4096][4096], writes compact P fp16.
// Launched per batch right after that batch's logits GEMM -> S rows L3-hot.
// ---------------------------------------------------------------------------
__global__ __launch_bounds__(256)
void softmax_f16(const float* __restrict__ S, u16* __restrict__ P)
{
    __shared__ float buf[4096];
    __shared__ float red[256];
    const float* p = S + (long)blockIdx.x * 4096;
    u16* o = P + (long)blockIdx.x * 4096;
    const int tid = threadIdx.x;

    float lmax = -3.4e38f;
    for (int i = tid; i < 4096; i += 256) {
        float x = p[i];
        buf[i] = x;
        lmax = fmaxf(lmax, x);
    }
    red[tid] = lmax;
    __syncthreads();
    for (int s = 128; s > 0; s >>= 1) {
        if (tid < s) red[tid] = fmaxf(red[tid], red[tid + s]);
        __syncthreads();
    }
    const float mx = red[0];
    __syncthreads();

    float lsum = 0.0f;
    for (int i = tid; i < 4096; i += 256) {
        float e = __expf(buf[i] - mx);
        buf[i] = e;
        lsum += e;
    }
    red[tid] = lsum;
    __syncthreads();
    for (int s = 128; s > 0; s >>= 1) {
        if (tid < s) red[tid] += red[tid + s];
        __syncthreads();
    }
    const float invs = 1.0f / red[0];
    __syncthreads();

    for (int i = tid; i < 4096; i += 256) o[i] = f2h(buf[i] * invs);
}

// ---------------------------------------------------------------------------
extern "C" void kernel_launch(void* const* d_in, const int* in_sizes, int n_in,
                              void* d_out, int out_size, void* d_ws, size_t ws_size,
                              hipStream_t stream)
{
    (void)in_sizes; (void)n_in; (void)out_size; (void)ws_size;
    constexpr int B = 4, C = 2048, R = 512, N = 4096;
    constexpr long NR = (long)N * R;     // 2,097,152
    constexpr long NC = (long)N * C;     // 8,388,608
    constexpr long NN = (long)N * N;     // 16,777,216
    constexpr long NQK = (long)N * 1024;

    const float* feature = (const float*)d_in[0];
    const float* W_[5]  = {(const float*)d_in[1],  (const float*)d_in[6],
                           (const float*)d_in[11], (const float*)d_in[16],
                           (const float*)d_in[21]};
    const float* G_[5]  = {(const float*)d_in[2],  (const float*)d_in[7],
                           (const float*)d_in[12], (const float*)d_in[17],
                           (const float*)d_in[22]};
    const float* Bb_[5] = {(const float*)d_in[3],  (const float*)d_in[8],
                           (const float*)d_in[13], (const float*)d_in[18],
                           (const float*)d_in[23]};
    const float* M_[5]  = {(const float*)d_in[4],  (const float*)d_in[9],
                           (const float*)d_in[14], (const float*)d_in[19],
                           (const float*)d_in[24]};
    const float* V_[5]  = {(const float*)d_in[5],  (const float*)d_in[10],
                           (const float*)d_in[15], (const float*)d_in[20],
                           (const float*)d_in[25]};

    // ---- workspace layout (bytes), ws = 512 MiB ----
    char* base = (char*)d_ws;
    size_t off = 0;
    // region0: S fp32 [B][N][N]; featT fp16 aliases its head (dead by logits)
    float* S     = (float*)base;
    u16*   featT = (u16*)base;
    off += (size_t)B * NN * 4;                         // 268,435,456
    u16* fT  = (u16*)(base + off);                     off += (size_t)B * NR * 2;
    u16* qkT = (u16*)(base + off);                     off += (size_t)B * NQK * 2;
    u16* vC  = (u16*)(base + off);                     off += (size_t)B * NR * 2;
    u16* gT  = (u16*)(base + off);                     off += (size_t)B * NR * 2;
    u16* Pc  = (u16*)(base + off);                     off += (size_t)B * NN * 2;
    // weights (fp16)
    u16* Wb_r  = (u16*)(base + off);  off += (size_t)R * C * 2;       // 2 MB
    u16* WbQK  = (u16*)(base + off);  off += (size_t)1024 * R * 2;    // 1 MB
    u16* Wb_v  = (u16*)(base + off);  off += (size_t)R * R * 2;       // 0.5 MB
    u16* Wb_u  = (u16*)(base + off);  off += (size_t)C * R * 2;       // 2 MB
    off = (off + 255) & ~(size_t)255;
    // BN params
    float* inv_r  = (float*)(base + off);  off += 8192;
    float* beta_r = (float*)(base + off);  off += 8192;
    float* invQK  = (float*)(base + off);  off += 8192;   // [1024]
    float* betaQK = (float*)(base + off);  off += 8192;   // [1024]
    float* inv_v  = (float*)(base + off);  off += 8192;
    float* beta_v = (float*)(base + off);  off += 8192;
    float* inv_u  = (float*)(base + off);  off += 8192;   // [2048]
    float* beta_u = (float*)(base + off);  off += 8192;

    float* out = (float*)d_out;
    const dim3 blk(256);
    const dim3 blk512(512);

    // ---- weight conversion + BN param precompute ----
    conv_weight<<<512, blk, 0, stream>>>(W_[0], G_[0], Bb_[0], M_[0], V_[0],
                                         Wb_r, inv_r, beta_r, R, (long)R * C);
    conv_weight<<<512, blk, 0, stream>>>(W_[1], G_[1], Bb_[1], M_[1], V_[1],
                                         WbQK, invQK, betaQK, R, (long)R * R);
    conv_weight<<<512, blk, 0, stream>>>(W_[2], G_[2], Bb_[2], M_[2], V_[2],
                                         WbQK + (size_t)R * R, invQK + R, betaQK + R,
                                         R, (long)R * R);
    conv_weight<<<512, blk, 0, stream>>>(W_[3], G_[3], Bb_[3], M_[3], V_[3],
                                         Wb_v, inv_v, beta_v, R, (long)R * R);
    conv_weight<<<512, blk, 0, stream>>>(W_[4], G_[4], Bb_[4], M_[4], V_[4],
                                         Wb_u, inv_u, beta_u, C, (long)C * R);

    // ---- feature transpose+convert: [B][C][N] f32 -> [B][N][C] fp16 ----
    transpose_conv<<<dim3(N / 32, C / 32, B), blk, 0, stream>>>(feature, featT, C, N);

    // ---- f = CBR(feature, r): batches merged as [16384][2048] x [512][2048]
    // grid (2,64) = 128 wgs, K=2048 ----
    gemm256<1, u16><<<dim3(R / 256, (B * N) / 256, 1), blk512, 0, stream>>>(
        featT, Wb_r, fT, inv_r, beta_r, nullptr,
        C, C, C, R, 0, 0, 0);

    // ---- q,k merged: [16384][512] x [1024][512], grid (4,64) = 256 ----
    gemm256<1, u16><<<dim3(1024 / 256, (B * N) / 256, 1), blk512, 0, stream>>>(
        fT, WbQK, qkT, invQK, betaQK, nullptr,
        R, R, R, 1024, 0, 0, 0);

    // ---- v = CBR(f), channel-major: per batch [512][512] x [4096][512],
    // grid (16,2,4) = 128 ----
    gemm256<2, u16><<<dim3(N / 256, R / 256, B), blk512, 0, stream>>>(
        Wb_v, fT, vC, inv_v, beta_v, nullptr,
        R, R, R, N, 0, NR, NR);

    // ---- logits + softmax PER BATCH (S[b] 67 MB stays L3-hot), grid 256 ----
    for (int b = 0; b < B; ++b) {
        gemm256<0, float><<<dim3(N / 256, N / 256, 1), blk512, 0, stream>>>(
            qkT + (long)b * NQK, qkT + (long)b * NQK + 512, S + (long)b * NN,
            nullptr, nullptr, nullptr,
            R, 1024, 1024, N, 0, 0, 0);
        softmax_f16<<<dim3(N), blk, 0, stream>>>(S + (long)b * NN,
                                                 Pc + (long)b * NN);
    }

    // ---- upd: per batch [4096][4096] x [512][4096], K=4096,
    // grid (2,16,4) = 128, +fT epilogue ----
    gemm256<3, u16><<<dim3(R / 256, N / 256, B), blk512, 0, stream>>>(
        Pc, vC, gT, nullptr, nullptr, fT,
        N, N, N, R, NN, NR, NR);

    // ---- out = CBR(f + upd, u): per batch [2048][512] x [4096][512],
    // grid (16,8,4) = 512 ----
    gemm256<2, float><<<dim3(N / 256, C / 256, B), blk512, 0, stream>>>(
        Wb_u, gT, out, inv_u, beta_u, nullptr,
        R, R, R, N, 0, NR, NC);
}

// Round 13
// 782.972 us; speedup vs baseline: 1.1597x; 1.1597x over previous
//
#include <hip/hip_runtime.h>

#define EPSV 1e-5f

typedef unsigned short u16;
typedef __attribute__((ext_vector_type(8))) _Float16 half8;
typedef __attribute__((ext_vector_type(4))) float floatx4;

__device__ __forceinline__ float h2f(u16 h) {
    return (float)__builtin_bit_cast(_Float16, h);
}
__device__ __forceinline__ u16 f2h(float f) {
    _Float16 h = (_Float16)f;
    return __builtin_bit_cast(u16, h);
}

// ---------------------------------------------------------------------------
// NT fp16 MFMA GEMM: D[i][j] = sum_k A[i][k] * B[j][k]
// A: [I][ldA] fp16 (K contiguous), B: [J][ldB] fp16 (K contiguous)
// Tile 128x128, BK=32, 256 threads (4 waves, 2x2 quadrants, 16 MFMAs each).
// SHALLOW 2-buffer pipeline -- the measured-best core after 5 structural
// experiments: deep counted-vmcnt (R6/R7 null), 128x64 tiles (R8 worse),
// split-K (R11 null net), 256^2 phase-split (R12 much worse). This problem's
// GEMM shapes cap this structure at ~500 TF; remaining wins are data-movement.
// MODE: 0 = plain, 1 = BN+ReLU per col j, 2 = BN+ReLU per row i,
//       3 = add fp16 tensor `addf`
// ---------------------------------------------------------------------------
template <int MODE, typename OUTT>
__global__ __launch_bounds__(256)
void gemm_nt(const u16* __restrict__ A, const u16* __restrict__ B,
             OUTT* __restrict__ C_,
             const float* __restrict__ inv_, const float* __restrict__ beta_,
             const u16* __restrict__ addf,
             int K, int ldA, int ldB, int ldC,
             long strideA, long strideB, long strideC)
{
    __shared__ u16 As[2][128 * 32];
    __shared__ u16 Bs[2][128 * 32];

    const int tid = threadIdx.x;
    const int w = tid >> 6;        // wave 0..3
    const int l = tid & 63;        // lane

    // XCD-chunked bijective swizzle: all our grids have nwg % 8 == 0.
    int bx = blockIdx.x, by = blockIdx.y, bz = blockIdx.z;
    {
        const int gx = gridDim.x, gy = gridDim.y;
        const int nwg = gx * gy * (int)gridDim.z;
        if ((nwg & 7) == 0) {
            const int lin = bx + gx * (by + gy * bz);
            const int swz = (lin & 7) * (nwg >> 3) + (lin >> 3);
            bx = swz % gx;
            const int t = swz / gx;
            by = t % gy;
            bz = t / gy;
        }
    }
    const int j0 = bx * 128;
    const int i0 = by * 128;

    const u16* Ab = A + (long)bz * strideA;
    const u16* Bb = B + (long)bz * strideB;

    // staging: per issue, wave w covers 16 rows (lane/4), granule (lane&3)*8
    const int srow = w * 16 + (l >> 2);   // 0..63 (+64 for second issue)
    const int skel = (l & 3) * 8;         // k element offset

    // compute mapping: wave quadrant
    const int i_base = (w >> 1) * 64;
    const int j_base = (w & 1) * 64;
    const int lm = l & 15;
    const int kq = l >> 4;                // 0..3

    floatx4 acc[4][4];
    #pragma unroll
    for (int a = 0; a < 4; ++a)
        #pragma unroll
        for (int b = 0; b < 4; ++b) acc[a][b] = (floatx4)(0.0f);

    auto stage = [&](int buf, int k0) {
        const u16* ga0 = Ab + (long)(i0 + srow) * ldA + k0 + skel;
        const u16* ga1 = Ab + (long)(i0 + 64 + srow) * ldA + k0 + skel;
        const u16* gb0 = Bb + (long)(j0 + srow) * ldB + k0 + skel;
        const u16* gb1 = Bb + (long)(j0 + 64 + srow) * ldB + k0 + skel;
        char* la0 = (char*)&As[buf][0] + w * 1024;
        char* la1 = (char*)&As[buf][0] + 4096 + w * 1024;
        char* lb0 = (char*)&Bs[buf][0] + w * 1024;
        char* lb1 = (char*)&Bs[buf][0] + 4096 + w * 1024;
        __builtin_amdgcn_global_load_lds(
            (const __attribute__((address_space(1))) unsigned int*)(const void*)ga0,
            (__attribute__((address_space(3))) unsigned int*)(void*)la0, 16, 0, 0);
        __builtin_amdgcn_global_load_lds(
            (const __attribute__((address_space(1))) unsigned int*)(const void*)ga1,
            (__attribute__((address_space(3))) unsigned int*)(void*)la1, 16, 0, 0);
        __builtin_amdgcn_global_load_lds(
            (const __attribute__((address_space(1))) unsigned int*)(const void*)gb0,
            (__attribute__((address_space(3))) unsigned int*)(void*)lb0, 16, 0, 0);
        __builtin_amdgcn_global_load_lds(
            (const __attribute__((address_space(1))) unsigned int*)(const void*)gb1,
            (__attribute__((address_space(3))) unsigned int*)(void*)lb1, 16, 0, 0);
    };

    const int nt = K >> 5;            // K-tiles of 32
    stage(0, 0);
    __syncthreads();
    int cur = 0;
    for (int t = 0; t < nt; ++t) {
        if (t + 1 < nt) stage(cur ^ 1, (t + 1) << 5);

        const u16* Ac = &As[cur][0];
        const u16* Bc = &Bs[cur][0];
        half8 af[4], bf[4];
        #pragma unroll
        for (int tt = 0; tt < 4; ++tt) {
            af[tt] = *(const half8*)&Ac[(i_base + tt * 16 + lm) * 32 + kq * 8];
            bf[tt] = *(const half8*)&Bc[(j_base + tt * 16 + lm) * 32 + kq * 8];
        }
        #pragma unroll
        for (int ti = 0; ti < 4; ++ti)
            #pragma unroll
            for (int tj = 0; tj < 4; ++tj)
                acc[ti][tj] = __builtin_amdgcn_mfma_f32_16x16x32_f16(
                    af[ti], bf[tj], acc[ti][tj], 0, 0, 0);
        __syncthreads();
        cur ^= 1;
    }

    OUTT* Cb = C_ + (long)bz * strideC;
    const u16* addb = (MODE == 3) ? addf + (long)bz * strideC : nullptr;
    #pragma unroll
    for (int ti = 0; ti < 4; ++ti) {
        #pragma unroll
        for (int tj = 0; tj < 4; ++tj) {
            const int jj = j0 + j_base + tj * 16 + lm;
            float cinv = 0.f, cbeta = 0.f;
            if (MODE == 1) { cinv = inv_[jj]; cbeta = beta_[jj]; }
            #pragma unroll
            for (int r = 0; r < 4; ++r) {
                const int ii = i0 + i_base + ti * 16 + kq * 4 + r;
                float val = acc[ti][tj][r];
                if (MODE == 1) val = fmaxf(val * cinv + cbeta, 0.0f);
                if (MODE == 2) {
                    float iv = inv_[ii], bt = beta_[ii];
                    val = fmaxf(val * iv + bt, 0.0f);
                }
                if (MODE == 3) val += h2f(addb[(long)ii * ldC + jj]);
                if (sizeof(OUTT) == 4) {
                    ((float*)Cb)[(long)ii * ldC + jj] = val;
                } else {
                    ((u16*)Cb)[(long)ii * ldC + jj] = f2h(val);
                }
            }
        }
    }
}

// ---------------------------------------------------------------------------
// weight fp32 -> fp16 + precompute BN inv/beta
// ---------------------------------------------------------------------------
__global__ __launch_bounds__(256)
void conv_weight(const float* __restrict__ W, const float* __restrict__ g,
                 const float* __restrict__ b, const float* __restrict__ m,
                 const float* __restrict__ v,
                 u16* __restrict__ Wb, float* __restrict__ inv_,
                 float* __restrict__ beta_, int cout, long n)
{
    for (long idx = (long)blockIdx.x * 256 + threadIdx.x; idx < n;
         idx += (long)gridDim.x * 256)
        Wb[idx] = f2h(W[idx]);
    int c = blockIdx.x * 256 + threadIdx.x;
    if (c < cout) {
        float iv = g[c] * rsqrtf(v[c] + EPSV);
        inv_[c] = iv;
        beta_[c] = b[c] - m[c] * iv;
    }
}

// ---------------------------------------------------------------------------
// feature [C][N] fp32 -> featT [N][C] fp16 (32x32 tiled transpose), per batch z
// ---------------------------------------------------------------------------
__global__ __launch_bounds__(256)
void transpose_conv(const float* __restrict__ in, u16* __restrict__ out,
                    int C, int N)
{
    __shared__ float t[32][33];
    const int n0 = blockIdx.x * 32, c0 = blockIdx.y * 32;
    const float* inb = in + (long)blockIdx.z * C * N;
    u16* outb = out + (long)blockIdx.z * C * N;
    const int tx = threadIdx.x & 31, ty = threadIdx.x >> 5;  // 32 x 8
    #pragma unroll
    for (int rr = 0; rr < 32; rr += 8)
        t[ty + rr][tx] = inb[(long)(c0 + ty + rr) * N + n0 + tx];
    __syncthreads();
    #pragma unroll
    for (int rr = 0; rr < 32; rr += 8)
        outb[(long)(n0 + ty + rr) * C + c0 + tx] = f2h(t[tx][ty + rr]);
}

// ---------------------------------------------------------------------------
// Row softmax for ONE batch: reads S fp16 [4096][4096] (half the traffic of
// the old fp32 S; S[b]=33.5 MB is L3-hot from the preceding logits GEMM),
// writes compact P fp16.
// ---------------------------------------------------------------------------
__global__ __launch_bounds__(256)
void softmax_f16(const u16* __restrict__ S, u16* __restrict__ P)
{
    __shared__ float buf[4096];
    __shared__ float red[256];
    const u16* p = S + (long)blockIdx.x * 4096;
    u16* o = P + (long)blockIdx.x * 4096;
    const int tid = threadIdx.x;

    float lmax = -3.4e38f;
    for (int i = tid; i < 4096; i += 256) {
        float x = h2f(p[i]);
        buf[i] = x;
        lmax = fmaxf(lmax, x);
    }
    red[tid] = lmax;
    __syncthreads();
    for (int s = 128; s > 0; s >>= 1) {
        if (tid < s) red[tid] = fmaxf(red[tid], red[tid + s]);
        __syncthreads();
    }
    const float mx = red[0];
    __syncthreads();

    float lsum = 0.0f;
    for (int i = tid; i < 4096; i += 256) {
        float e = __expf(buf[i] - mx);
        buf[i] = e;
        lsum += e;
    }
    red[tid] = lsum;
    __syncthreads();
    for (int s = 128; s > 0; s >>= 1) {
        if (tid < s) red[tid] += red[tid + s];
        __syncthreads();
    }
    const float invs = 1.0f / red[0];
    __syncthreads();

    for (int i = tid; i < 4096; i += 256) o[i] = f2h(buf[i] * invs);
}

// ---------------------------------------------------------------------------
extern "C" void kernel_launch(void* const* d_in, const int* in_sizes, int n_in,
                              void* d_out, int out_size, void* d_ws, size_t ws_size,
                              hipStream_t stream)
{
    (void)in_sizes; (void)n_in; (void)out_size; (void)ws_size;
    constexpr int B = 4, C = 2048, R = 512, N = 4096;
    constexpr long NR = (long)N * R;     // 2,097,152
    constexpr long NC = (long)N * C;     // 8,388,608
    constexpr long NN = (long)N * N;     // 16,777,216
    constexpr long NQK = (long)N * 1024;

    const float* feature = (const float*)d_in[0];
    const float* W_[5]  = {(const float*)d_in[1],  (const float*)d_in[6],
                           (const float*)d_in[11], (const float*)d_in[16],
                           (const float*)d_in[21]};
    const float* G_[5]  = {(const float*)d_in[2],  (const float*)d_in[7],
                           (const float*)d_in[12], (const float*)d_in[17],
                           (const float*)d_in[22]};
    const float* Bb_[5] = {(const float*)d_in[3],  (const float*)d_in[8],
                           (const float*)d_in[13], (const float*)d_in[18],
                           (const float*)d_in[23]};
    const float* M_[5]  = {(const float*)d_in[4],  (const float*)d_in[9],
                           (const float*)d_in[14], (const float*)d_in[19],
                           (const float*)d_in[24]};
    const float* V_[5]  = {(const float*)d_in[5],  (const float*)d_in[10],
                           (const float*)d_in[15], (const float*)d_in[20],
                           (const float*)d_in[25]};

    // ---- workspace layout (bytes), ws = 512 MiB ----
    char* base = (char*)d_ws;
    size_t off = 0;
    // region0 (134 MB): S fp16 [B][N][N] during logits/softmax.
    // featT fp16 [B][N][C] (67 MB) aliases its head -- dead before logits.
    u16* S     = (u16*)base;
    u16* featT = (u16*)base;
    off += (size_t)B * NN * 2;                         // 134,217,728
    u16* fT  = (u16*)(base + off);                     off += (size_t)B * NR * 2;
    u16* qkT = (u16*)(base + off);                     off += (size_t)B * NQK * 2;
    u16* vC  = (u16*)(base + off);                     off += (size_t)B * NR * 2;
    u16* gT  = (u16*)(base + off);                     off += (size_t)B * NR * 2;
    u16* Pc  = (u16*)(base + off);                     off += (size_t)B * NN * 2;
    // weights (fp16)
    u16* Wb_r  = (u16*)(base + off);  off += (size_t)R * C * 2;       // 2 MB
    u16* WbQK  = (u16*)(base + off);  off += (size_t)1024 * R * 2;    // 1 MB
    u16* Wb_v  = (u16*)(base + off);  off += (size_t)R * R * 2;       // 0.5 MB
    u16* Wb_u  = (u16*)(base + off);  off += (size_t)C * R * 2;       // 2 MB
    off = (off + 255) & ~(size_t)255;
    // BN params
    float* inv_r  = (float*)(base + off);  off += 8192;
    float* beta_r = (float*)(base + off);  off += 8192;
    float* invQK  = (float*)(base + off);  off += 8192;   // [1024]
    float* betaQK = (float*)(base + off);  off += 8192;   // [1024]
    float* inv_v  = (float*)(base + off);  off += 8192;
    float* beta_v = (float*)(base + off);  off += 8192;
    float* inv_u  = (float*)(base + off);  off += 8192;   // [2048]
    float* beta_u = (float*)(base + off);  off += 8192;

    float* out = (float*)d_out;
    const dim3 blk(256);

    // ---- weight conversion + BN param precompute ----
    conv_weight<<<512, blk, 0, stream>>>(W_[0], G_[0], Bb_[0], M_[0], V_[0],
                                         Wb_r, inv_r, beta_r, R, (long)R * C);
    conv_weight<<<512, blk, 0, stream>>>(W_[1], G_[1], Bb_[1], M_[1], V_[1],
                                         WbQK, invQK, betaQK, R, (long)R * R);
    conv_weight<<<512, blk, 0, stream>>>(W_[2], G_[2], Bb_[2], M_[2], V_[2],
                                         WbQK + (size_t)R * R, invQK + R, betaQK + R,
                                         R, (long)R * R);
    conv_weight<<<512, blk, 0, stream>>>(W_[3], G_[3], Bb_[3], M_[3], V_[3],
                                         Wb_v, inv_v, beta_v, R, (long)R * R);
    conv_weight<<<512, blk, 0, stream>>>(W_[4], G_[4], Bb_[4], M_[4], V_[4],
                                         Wb_u, inv_u, beta_u, C, (long)C * R);

    // ---- feature transpose+convert: [B][C][N] f32 -> [B][N][C] fp16 ----
    transpose_conv<<<dim3(N / 32, C / 32, B), blk, 0, stream>>>(feature, featT, C, N);

    // ---- f = CBR(feature, r): grid 512 ----
    gemm_nt<1, u16><<<dim3(R / 128, N / 128, B), blk, 0, stream>>>(
        featT, Wb_r, fT, inv_r, beta_r, nullptr,
        C, C, C, R, NC, 0, NR);

    // ---- q,k merged: qkT [B][N][1024], grid 1024 ----
    gemm_nt<1, u16><<<dim3(1024 / 128, N / 128, B), blk, 0, stream>>>(
        fT, WbQK, qkT, invQK, betaQK, nullptr,
        R, R, R, 1024, NR, 0, NQK);

    // ---- v = CBR(f), channel-major: vC [B][R][N], grid 512 ----
    gemm_nt<2, u16><<<dim3(N / 128, R / 128, B), blk, 0, stream>>>(
        Wb_v, fT, vC, inv_v, beta_v, nullptr,
        R, R, R, N, 0, NR, NR);

    // ---- logits (fp16 S, half the write traffic) + softmax PER BATCH:
    // S[b] = 33.5 MB stays L3-hot for the softmax that consumes it. ----
    for (int b = 0; b < B; ++b) {
        gemm_nt<0, u16><<<dim3(N / 128, N / 128, 1), blk, 0, stream>>>(
            qkT + (long)b * NQK, qkT + (long)b * NQK + 512, S + (long)b * NN,
            nullptr, nullptr, nullptr,
            R, 1024, 1024, N, 0, 0, 0);
        softmax_f16<<<dim3(N), blk, 0, stream>>>(S + (long)b * NN,
                                                 Pc + (long)b * NN);
    }

    // ---- upd: gT[b][n][c] = fT + sum_m P[n][m]*vC[c][m], grid 512 ----
    gemm_nt<3, u16><<<dim3(R / 128, N / 128, B), blk, 0, stream>>>(
        Pc, vC, gT, nullptr, nullptr, fT,
        N, N, N, R, NN, NR, NR);

    // ---- out = CBR(f + upd, u): grid 2048 ----
    gemm_nt<2, float><<<dim3(N / 128, C / 128, B), blk, 0, stream>>>(
        Wb_u, gT, out, inv_u, beta_u, nullptr,
        R, R, R, N, 0, NR, NC);
}